// Round 8
// baseline (2969.721 us; speedup 1.0000x reference)
//
#include <hip/hip_runtime.h>

typedef unsigned short u16;
typedef __attribute__((ext_vector_type(8))) __bf16 bf16x8;
typedef __attribute__((ext_vector_type(4))) float f32x4;
typedef __attribute__((ext_vector_type(4))) unsigned int u32x4;
typedef __attribute__((ext_vector_type(2))) unsigned int u32x2;

// ---------- workspace layout (bytes) ----------
#define GX_OFF   0ull                      // gates_x [32768][1024][4] bf16 = 268435456
#define FT_OFF   268435456ull              // ft      [32768][1024]    bf16 = 67108864
#define WT_OFF   335544320ull              // Wt      [4096][2048]     bf16 = 16777216
#define W1T_OFF  352321536ull              // W1t     [2048][256]      bf16 = 1048576 (dead after k_field)
#define CB_OFF   352321536ull              // cbuf [64][1024] f32 = 262144  (overlays W1t; flag region in coop path)
#define HF_OFF   352583680ull              // hfin [64][1024] f32 = 262144  (overlays W1t)
#define HB_OFF   353370112ull              // hbuf [2][64][1024] bf16 = 262144
#define WS_NEED  (HB_OFF + 262144ull)      // = 353632256

#define NBLK 256

__device__ __forceinline__ float b2f(u16 u) {
    unsigned x = ((unsigned)u) << 16;
    return __builtin_bit_cast(float, x);
}
__device__ __forceinline__ u16 f2b(float f) {   // rne f32->bf16
    unsigned u = __builtin_bit_cast(unsigned, f);
    unsigned r = (u + 0x7FFFu + ((u >> 16) & 1u)) >> 16;
    return (u16)r;
}
__device__ __forceinline__ float fsigm(float x) {
    return __builtin_amdgcn_rcpf(1.f + __expf(-x));
}
__device__ __forceinline__ float ftanh2(float x) {
    return 2.f * __builtin_amdgcn_rcpf(1.f + __expf(-2.f * x)) - 1.f;
}
__device__ __forceinline__ bf16x8 ld_frag(const u16* p) {
    u32x4 v = *(const u32x4*)p;
    return __builtin_bit_cast(bf16x8, v);
}
__device__ __forceinline__ f32x4 mfma16(bf16x8 a, bf16x8 b, f32x4 c) {
    return __builtin_amdgcn_mfma_f32_16x16x32_bf16(a, b, c, 0, 0, 0);
}
// load 8 f32, convert to 8 bf16 packed in u32x4
__device__ __forceinline__ u32x4 cvt8(const float* p) {
    f32x4 a = *(const f32x4*)p;
    f32x4 b = *(const f32x4*)(p + 4);
    u32x4 r;
    r.x = (unsigned)f2b(a[0]) | ((unsigned)f2b(a[1]) << 16);
    r.y = (unsigned)f2b(a[2]) | ((unsigned)f2b(a[3]) << 16);
    r.z = (unsigned)f2b(b[0]) | ((unsigned)f2b(b[1]) << 16);
    r.w = (unsigned)f2b(b[2]) | ((unsigned)f2b(b[3]) << 16);
    return r;
}

// ALL cross-block communication at system scope (sc0 sc1): L1+L2 bypass, the
// memory-side Infinity Cache is the coherence point. Proven replay-safe (r2/r3/r6).
// L2-scope (sc0-only) is NOT replay-safe (r5). Data-embedded tag polling (r7)
// regressed: poll re-reads must stay 4B/lane, bulk fetch exactly once.
__device__ __forceinline__ u32x4 ld16_coh(const u16* p) {
    u32x4 v;
    asm volatile("global_load_dwordx4 %0, %1, off sc0 sc1" : "=v"(v) : "v"(p));
    return v;
}
__device__ __forceinline__ void st2_coh(u16* p, u16 val) {
    unsigned v = val;
    asm volatile("global_store_short %0, %1, off sc0 sc1" :: "v"(p), "v"(v) : "memory");
}
__device__ __forceinline__ void st4_coh(unsigned* p, unsigned v) {
    asm volatile("global_store_dword %0, %1, off sc0 sc1" :: "v"(p), "v"(v) : "memory");
}
__device__ __forceinline__ unsigned ld4_coh_wait(const unsigned* p) {
    unsigned v;
    asm volatile("global_load_dword %0, %1, off sc0 sc1\n\ts_waitcnt vmcnt(0)"
                 : "=v"(v) : "v"(p) : "memory");
    return v;
}

// ---------- transpose+cast: out_bf16[c][r] = f2b(in_f32[r][c]) ----------
__global__ void k_transpose(const float* __restrict__ in, u16* __restrict__ out, int R, int C) {
    __shared__ u16 tl[64][65];
    int tx = threadIdx.x, ty = threadIdx.y;
    int c0 = blockIdx.x * 64, r0 = blockIdx.y * 64;
#pragma unroll
    for (int i = 0; i < 16; i++) {
        int a = ty + i * 4;
        tl[a][tx] = f2b(in[(size_t)(r0 + a) * C + c0 + tx]);
    }
    __syncthreads();
#pragma unroll
    for (int i = 0; i < 16; i++) {
        int a = ty + i * 4;
        out[(size_t)(c0 + a) * R + r0 + tx] = tl[tx][a];
    }
}

// ---------- field GEMM: ft = sigmoid(F@W1[:, :1024]+b) * tanh(F@W1[:, 1024:]+b) ----------
// Rows (bb, t) with t >= len[bb] are dead downstream — skip tiles entirely past len.
__global__ __launch_bounds__(256) void k_field(const float* __restrict__ F, const u16* __restrict__ W1t,
                                               const float* __restrict__ bW1, const int* __restrict__ len,
                                               u16* __restrict__ ftw) {
    int m0 = blockIdx.y * 128;
    if ((m0 & 511) >= len[m0 >> 9]) return;   // whole tile beyond this row's length
    int n0 = blockIdx.x * 64;
    __shared__ u16 As[128 * 40];
    __shared__ u16 Bs[128 * 40];
    int tid = threadIdx.x, w = tid >> 6, lane = tid & 63, quad = lane >> 4, l16 = lane & 15;
    f32x4 acc[2][8];
#pragma unroll
    for (int mt = 0; mt < 2; mt++)
#pragma unroll
        for (int nt = 0; nt < 8; nt++) acc[mt][nt] = (f32x4){0.f, 0.f, 0.f, 0.f};

    for (int kc = 0; kc < 8; kc++) {
        __syncthreads();
#pragma unroll
        for (int it = 0; it < 2; it++) {
            int q = tid + it * 256, row = q >> 2, sub = q & 3;
            u32x4 va = cvt8(F + (size_t)(m0 + row) * 256 + kc * 32 + sub * 8);
            *(u32x4*)(As + row * 40 + sub * 8) = va;
            int brow = (row < 64) ? (n0 + row) : (1024 + n0 + row - 64);
            u32x4 vb = *(const u32x4*)(W1t + (size_t)brow * 256 + kc * 32 + sub * 8);
            *(u32x4*)(Bs + row * 40 + sub * 8) = vb;
        }
        __syncthreads();
        bf16x8 af[2], bfr[8];
#pragma unroll
        for (int mt = 0; mt < 2; mt++) af[mt] = ld_frag(As + (w * 32 + mt * 16 + l16) * 40 + quad * 8);
#pragma unroll
        for (int nt = 0; nt < 8; nt++) bfr[nt] = ld_frag(Bs + (nt * 16 + l16) * 40 + quad * 8);
#pragma unroll
        for (int mt = 0; mt < 2; mt++)
#pragma unroll
            for (int nt = 0; nt < 8; nt++) acc[mt][nt] = mfma16(af[mt], bfr[nt], acc[mt][nt]);
    }
#pragma unroll
    for (int nth = 0; nth < 4; nth++) {
        float br = bW1[n0 + nth * 16 + l16];
        float bd = bW1[1024 + n0 + nth * 16 + l16];
#pragma unroll
        for (int mt = 0; mt < 2; mt++) {
#pragma unroll
            for (int j = 0; j < 4; j++) {
                int r = m0 + w * 32 + mt * 16 + quad * 4 + j;
                float rv = acc[mt][nth][j] + br;
                float dv = acc[mt][nth + 4][j] + bd;
                ftw[(size_t)r * 1024 + n0 + nth * 16 + l16] = f2b(fsigm(rv) * ftanh2(dv));
            }
        }
    }
}

// ---------- x GEMM: gx[r][H][g] = X@W[:1024,:] + bW (gate-interleaved, bf16 store) ----------
__global__ __launch_bounds__(256) void k_xgemm(const float* __restrict__ X, const u16* __restrict__ Wt,
                                               const float* __restrict__ bWv, const int* __restrict__ len,
                                               u16* __restrict__ gx) {
    int m0 = blockIdx.y * 128;
    if ((m0 & 511) >= len[m0 >> 9]) return;   // whole tile beyond this row's length
    int n0 = blockIdx.x * 128;
    __shared__ u16 As[128 * 40];
    __shared__ u16 Bs[128 * 40];
    int tid = threadIdx.x, w = tid >> 6, lane = tid & 63, quad = lane >> 4, l16 = lane & 15;
    int mq = (w & 1) * 64, nq = (w >> 1) * 64;
    f32x4 acc[4][4];
#pragma unroll
    for (int mt = 0; mt < 4; mt++)
#pragma unroll
        for (int nt = 0; nt < 4; nt++) acc[mt][nt] = (f32x4){0.f, 0.f, 0.f, 0.f};

    for (int kc = 0; kc < 32; kc++) {
        __syncthreads();
#pragma unroll
        for (int it = 0; it < 2; it++) {
            int q = tid + it * 256, row = q >> 2, sub = q & 3;
            u32x4 va = cvt8(X + (size_t)(m0 + row) * 1024 + kc * 32 + sub * 8);
            *(u32x4*)(As + row * 40 + sub * 8) = va;
            u32x4 vb = *(const u32x4*)(Wt + (size_t)(n0 + row) * 2048 + kc * 32 + sub * 8);
            *(u32x4*)(Bs + row * 40 + sub * 8) = vb;
        }
        __syncthreads();
        bf16x8 af[4], bfr[4];
#pragma unroll
        for (int mt = 0; mt < 4; mt++) af[mt] = ld_frag(As + (mq + mt * 16 + l16) * 40 + quad * 8);
#pragma unroll
        for (int nt = 0; nt < 4; nt++) bfr[nt] = ld_frag(Bs + (nq + nt * 16 + l16) * 40 + quad * 8);
#pragma unroll
        for (int mt = 0; mt < 4; mt++)
#pragma unroll
            for (int nt = 0; nt < 4; nt++) acc[mt][nt] = mfma16(af[mt], bfr[nt], acc[mt][nt]);
    }
#pragma unroll
    for (int nt = 0; nt < 4; nt++) {
        int gcol = n0 + nq + nt * 16 + l16;
        int hcol = gcol & 1023, g = gcol >> 10;
        float bw = bWv[gcol];
#pragma unroll
        for (int mt = 0; mt < 4; mt++) {
#pragma unroll
            for (int j = 0; j < 4; j++) {
                int r = m0 + mq + mt * 16 + quad * 4 + j;
                gx[(size_t)r * 4096 + hcol * 4 + g] = f2b(acc[mt][nt][j] + bw);
            }
        }
    }
}

// ---------- zero-init recurrent state (+ flag region overlaying cbuf in coop path) ----------
__global__ void k_zero(u16* __restrict__ hbuf, float* __restrict__ cbuf, float* __restrict__ hfin) {
    int idx = blockIdx.x * 1024 + threadIdx.x;  // 64k threads
    hbuf[idx] = 0; hbuf[65536 + idx] = 0;
    cbuf[idx] = 0.f; hfin[idx] = 0.f;
}

// ---------- persistent cooperative LSTM: all 512 steps in one kernel ----------
// grid = 256 blocks = 4 bbg (16-row batch slices) x 64 wg (16 H-cols).
// r6 protocol (drain-then-flag, monotone flags, all sc0|sc1) with producer-side
// serialization removed:
//  * per-WAVE drain + flag: vmcnt is per-wave, so each wave drains its own 64
//    h-stores and lane 0 publishes flag[bbg][wg][w] — no block barrier, no funnel.
//  * consumer wave w needs producer blocks wg' in [16w,16w+16) x 4 waves
//    = 64 flags = one per lane (4B/lane poll, bulk h fetched exactly once).
//  * LDS red[] double-buffered by parity -> ONE raw s_barrier per step
//    (lgkmcnt-only drain; no vmcnt drain in the barrier path).
__global__ __launch_bounds__(256, 1) void k_lstm(const u16* __restrict__ Wt, const u16* __restrict__ gx,
                                                 const u16* __restrict__ ftw, const int* __restrict__ len,
                                                 float* __restrict__ out, u16* __restrict__ hbuf,
                                                 unsigned* __restrict__ bar) {
    __shared__ __align__(16) float red[2][4 * 64 * 20];
    int tid = threadIdx.x;
    int w = tid >> 6, lane = tid & 63, quad = lane >> 4, l16 = lane & 15;
    int blk = blockIdx.x;
    int bbg = blk & 3, wg = blk >> 2;

    // ---- one-time: weights into registers. wave w owns K range [w*256, w*256+256) ----
    bf16x8 breg[8][4];
#pragma unroll
    for (int kk = 0; kk < 8; kk++)
#pragma unroll
        for (int nt = 0; nt < 4; nt++) {
            size_t gcol = (size_t)nt * 1024 + wg * 16 + l16;   // gate nt, hcol wg*16+l16
            breg[kk][nt] = ld_frag(Wt + gcol * 2048 + 1024 + w * 256 + kk * 32 + quad * 8);
        }

    // per-thread epilogue ownership: one (bb, Hcol) pair
    int bbl = tid >> 4, hc = tid & 15;
    int bb = bbg * 16 + bbl;
    int Hcol = wg * 16 + hc;
    int mylen = len[bb];
    float hreg = 0.f, creg = 0.f;

    // flag lines: ((bbg*64 + wg)*4 + wave) * 32B, inside zeroed cbuf region (32KB)
    unsigned* myflag = bar + (((size_t)(bbg * 64 + wg)) * 4 + (size_t)w) * 8;
    // consumer lane l polls flag of producer block 16w+(l>>2), wave (l&3)
    const unsigned* pollp = bar + (((size_t)(bbg * 64 + 16 * w + (lane >> 2))) * 4
                                   + (size_t)(lane & 3)) * 8;

    // prefetch t=0 epilogue operands
    u32x2 gq = *(const u32x2*)(gx + ((size_t)bb * 512) * 4096 + (size_t)Hcol * 4);
    float ftv = b2f(ftw[((size_t)bb * 512) * 1024 + Hcol]);

    for (int t = 0; t < 512; t++) {
        const u16* hb = hbuf + (t & 1) * 65536;
        u16* hbn = hbuf + ((t + 1) & 1) * 65536;

        // ---- h @ Wh partial. A rows read coherently from L3 (writers were other blocks).
        u32x4 av[8];
#pragma unroll
        for (int kk = 0; kk < 8; kk++) {
            const u16* ap = hb + (size_t)(bbg * 16 + l16) * 1024 + w * 256 + kk * 32 + quad * 8;
            av[kk] = ld16_coh(ap);
        }
        asm volatile("s_waitcnt vmcnt(0)" ::: "memory");
        __builtin_amdgcn_sched_barrier(0);   // keep MFMAs below the waitcnt (rule #18)

        f32x4 acc[4];
#pragma unroll
        for (int nt = 0; nt < 4; nt++) acc[nt] = (f32x4){0.f, 0.f, 0.f, 0.f};
#pragma unroll
        for (int kk = 0; kk < 8; kk++) {
            bf16x8 af = __builtin_bit_cast(bf16x8, av[kk]);
#pragma unroll
            for (int nt = 0; nt < 4; nt++) acc[nt] = mfma16(af, breg[kk][nt], acc[nt]);
        }
        float* rp = red[t & 1];
#pragma unroll
        for (int nt = 0; nt < 4; nt++)
            *(f32x4*)&rp[(w * 64 + nt * 16 + l16) * 20 + quad * 4] = acc[nt];
        // single raw barrier: only LDS writes must be visible; parity double-buffer
        // protects against next-step overwrite. No vmcnt drain here.
        asm volatile("s_waitcnt lgkmcnt(0)" ::: "memory");
        __builtin_amdgcn_sched_barrier(0);
        __builtin_amdgcn_s_barrier();
        __builtin_amdgcn_sched_barrier(0);

        // cross-wave K-reduction (same order as fallback k_step: w = 0..3)
        float G[4];
#pragma unroll
        for (int g = 0; g < 4; g++) {
            int c = g * 16 + hc;
            G[g] = rp[(0 * 64 + c) * 20 + bbl] + rp[(1 * 64 + c) * 20 + bbl]
                 + rp[(2 * 64 + c) * 20 + bbl] + rp[(3 * 64 + c) * 20 + bbl];
        }
        float iv = G[0] + b2f((u16)(gq.x & 0xffff));
        float jv = G[1] + b2f((u16)(gq.x >> 16));
        float fv = G[2] + b2f((u16)(gq.y & 0xffff));
        float ov = G[3] + b2f((u16)(gq.y >> 16));
        float cn = fsigm(fv + 1.f) * creg + fsigm(iv) * ftanh2(jv) + ftv;
        float hn = fsigm(ov) * ftanh2(cn);
        bool act = t < mylen;
        hreg = act ? hn : hreg;
        creg = act ? cn : creg;
        // critical cross-block edge FIRST: h write-through, per-wave drain, flag
        st2_coh(hbn + bb * 1024 + Hcol, f2b(hreg));
        asm volatile("s_waitcnt vmcnt(0)" ::: "memory");
        if (t != 511) {
            unsigned gen = (unsigned)(t + 1);
            if (lane == 0) st4_coh(myflag, gen);
            // off-critical-path work while the flag flies / peers finish
            out[(size_t)bb * 524288 + (size_t)t * 1024 + Hcol] = act ? hn : 0.f;
            size_t rowi = (size_t)bb * 512 + (t + 1);
            gq = *(const u32x2*)(gx + rowi * 4096 + (size_t)Hcol * 4);
            ftv = b2f(ftw[rowi * 1024 + Hcol]);
            // hot poll: one 4B load per lane covers all 64 producer waves
            for (;;) {
                unsigned v = ld4_coh_wait(pollp);
                if (__all((int)(v >= gen))) break;
            }
        } else {
            out[(size_t)bb * 524288 + (size_t)t * 1024 + Hcol] = act ? hn : 0.f;
        }
    }
    // final states straight from registers (replaces k_fin)
    out[33554432 + (size_t)bb * 1024 + Hcol] = hreg;
    out[33554432 + 65536 + (size_t)bb * 1024 + Hcol] = creg;
}

// ---------- fallback: one LSTM time-step (512 sequential launches) ----------
__global__ __launch_bounds__(256) void k_step(const u16* __restrict__ Wt, const u16* __restrict__ gx,
                                              const u16* __restrict__ ftw, const int* __restrict__ len,
                                              float* __restrict__ out, u16* __restrict__ hbuf,
                                              float* __restrict__ cbuf, float* __restrict__ hfin, int t) {
    int wg = blockIdx.x;
    int tid = threadIdx.x, w = tid >> 6, lane = tid & 63, quad = lane >> 4, l16 = lane & 15;
    __shared__ float red[4 * 64 * 68];  // [wave][c][row(+pad)]

    const u16* hb = hbuf + (t & 1) * 65536;
    u16* hbn = hbuf + ((t + 1) & 1) * 65536;

    f32x4 acc[4][4];
#pragma unroll
    for (int mt = 0; mt < 4; mt++)
#pragma unroll
        for (int nt = 0; nt < 4; nt++) acc[mt][nt] = (f32x4){0.f, 0.f, 0.f, 0.f};

#pragma unroll
    for (int kk = 0; kk < 8; kk++) {
        bf16x8 af[4], bq[4];
#pragma unroll
        for (int mt = 0; mt < 4; mt++)
            af[mt] = ld_frag(hb + (mt * 16 + l16) * 1024 + w * 256 + kk * 32 + quad * 8);
#pragma unroll
        for (int nt = 0; nt < 4; nt++) {
            int c = nt * 16 + l16;
            int gcol = (c & 3) * 1024 + wg * 16 + (c >> 2);
            bq[nt] = ld_frag(Wt + (size_t)gcol * 2048 + 1024 + w * 256 + kk * 32 + quad * 8);
        }
#pragma unroll
        for (int mt = 0; mt < 4; mt++)
#pragma unroll
            for (int nt = 0; nt < 4; nt++) acc[mt][nt] = mfma16(af[mt], bq[nt], acc[mt][nt]);
    }

#pragma unroll
    for (int mt = 0; mt < 4; mt++)
#pragma unroll
        for (int nt = 0; nt < 4; nt++)
            *(f32x4*)&red[(w * 64 + nt * 16 + l16) * 68 + mt * 16 + quad * 4] = acc[mt][nt];
    __syncthreads();

    int hc = tid & 15, rg = tid >> 4;
    int Hcol = wg * 16 + hc;
    f32x4 Gv[4];
#pragma unroll
    for (int g = 0; g < 4; g++) {
        int c = hc * 4 + g;
        f32x4 s = *(f32x4*)&red[(0 * 64 + c) * 68 + rg * 4];
#pragma unroll
        for (int wq = 1; wq < 4; wq++) s += *(f32x4*)&red[(wq * 64 + c) * 68 + rg * 4];
        Gv[g] = s;
    }

#pragma unroll
    for (int j = 0; j < 4; j++) {
        int bb = rg * 4 + j;
        size_t rowi = (size_t)bb * 512 + t;
        u32x2 gq = *(const u32x2*)(gx + rowi * 4096 + (size_t)Hcol * 4);
        float iv = Gv[0][j] + b2f((u16)(gq.x & 0xffff));
        float jv = Gv[1][j] + b2f((u16)(gq.x >> 16));
        float fv = Gv[2][j] + b2f((u16)(gq.y & 0xffff));
        float ov = Gv[3][j] + b2f((u16)(gq.y >> 16));
        float ftv = b2f(ftw[rowi * 1024 + Hcol]);
        float cprev = cbuf[bb * 1024 + Hcol];
        float hprev = hfin[bb * 1024 + Hcol];
        float cn = fsigm(fv + 1.f) * cprev + fsigm(iv) * ftanh2(jv) + ftv;
        float hn = fsigm(ov) * ftanh2(cn);
        bool act = t < len[bb];
        out[(size_t)bb * 524288 + (size_t)t * 1024 + Hcol] = act ? hn : 0.f;
        hbn[bb * 1024 + Hcol] = f2b(act ? hn : hprev);
        cbuf[bb * 1024 + Hcol] = act ? cn : cprev;
        hfin[bb * 1024 + Hcol] = act ? hn : hprev;
    }
}

// ---------- fallback final state writeout (f32) ----------
__global__ void k_fin(const float* __restrict__ hfin, const float* __restrict__ cbuf,
                      float* __restrict__ out) {
    int idx = blockIdx.x * 1024 + threadIdx.x;  // 65536
    out[33554432 + idx] = hfin[idx];
    out[33554432 + 65536 + idx] = cbuf[idx];
}

extern "C" void kernel_launch(void* const* d_in, const int* in_sizes, int n_in,
                              void* d_out, int out_size, void* d_ws, size_t ws_size,
                              hipStream_t stream) {
    (void)in_sizes; (void)n_in; (void)out_size;
    if (ws_size < WS_NEED) return;

    const float* X   = (const float*)d_in[0];
    const float* F   = (const float*)d_in[1];
    const int*   len = (const int*)d_in[2];
    const float* W   = (const float*)d_in[3];
    const float* bW  = (const float*)d_in[4];
    const float* W1  = (const float*)d_in[5];
    const float* bW1 = (const float*)d_in[6];
    float* out = (float*)d_out;

    char* ws = (char*)d_ws;
    u16*   gx   = (u16*)(ws + GX_OFF);
    u16*   ftw  = (u16*)(ws + FT_OFF);
    u16*   Wt   = (u16*)(ws + WT_OFF);
    u16*   W1t  = (u16*)(ws + W1T_OFF);
    float* cbuf = (float*)(ws + CB_OFF);   // overlays W1t (dead after k_field); flag region in coop path
    float* hfin = (float*)(ws + HF_OFF);   // overlays W1t (dead after k_field)
    u16*   hbuf = (u16*)(ws + HB_OFF);

    k_transpose<<<dim3(64, 32), dim3(64, 4), 0, stream>>>(W, Wt, 2048, 4096);
    k_transpose<<<dim3(32, 4), dim3(64, 4), 0, stream>>>(W1, W1t, 256, 2048);
    k_field<<<dim3(16, 256), 256, 0, stream>>>(F, W1t, bW1, len, ftw);
    k_xgemm<<<dim3(32, 256), 256, 0, stream>>>(X, Wt, bW, len, gx);
    k_zero<<<64, 1024, 0, stream>>>(hbuf, cbuf, hfin);   // zeroes hbuf + flag region

    unsigned* bar = (unsigned*)cbuf;
    void* args[7] = {(void*)&Wt, (void*)&gx, (void*)&ftw, (void*)&len,
                     (void*)&out, (void*)&hbuf, (void*)&bar};
    hipError_t e = hipLaunchCooperativeKernel((const void*)k_lstm, dim3(NBLK), dim3(256),
                                              args, 0, stream);
    if (e != hipSuccess) {
        // fallback: proven 512-launch path (cbuf/hfin still zeroed and unaliased here)
        for (int t = 0; t < 512; t++)
            k_step<<<64, 256, 0, stream>>>(Wt, gx, ftw, len, out, hbuf, cbuf, hfin, t);
        k_fin<<<64, 1024, 0, stream>>>(hfin, cbuf, out);
    }
}

// Round 9
// 2302.110 us; speedup vs baseline: 1.2900x; 1.2900x over previous
//
#include <hip/hip_runtime.h>

typedef unsigned short u16;
typedef __attribute__((ext_vector_type(8))) __bf16 bf16x8;
typedef __attribute__((ext_vector_type(4))) float f32x4;
typedef __attribute__((ext_vector_type(4))) unsigned int u32x4;
typedef __attribute__((ext_vector_type(2))) unsigned int u32x2;

// ---------- workspace layout (bytes) ----------
#define GX_OFF   0ull                      // gates_x [32768][1024][4] bf16 = 268435456
#define FT_OFF   268435456ull              // ft      [32768][1024]    bf16 = 67108864
#define WT_OFF   335544320ull              // Wt      [4096][2048]     bf16 = 16777216
#define W1T_OFF  352321536ull              // W1t     [2048][256]      bf16 = 1048576 (dead after k_field)
#define CB_OFF   352321536ull              // cbuf [64][1024] f32 = 262144  (overlays W1t; flag region in coop path)
#define HF_OFF   352583680ull              // hfin [64][1024] f32 = 262144  (overlays W1t)
#define HB_OFF   353370112ull              // hbuf [2][64][1024] bf16 = 262144 (fallback layout; coop uses chunked)
#define WS_NEED  (HB_OFF + 262144ull)      // = 353632256
// coop path chunked h in the same HB region: hc[2][4 bbg][64 wg][16 row][16 col]
// bf16 = 2 x 65536 u16 — each producer block owns ONE contiguous 512B chunk.

#define NBLK 256

__device__ __forceinline__ float b2f(u16 u) {
    unsigned x = ((unsigned)u) << 16;
    return __builtin_bit_cast(float, x);
}
__device__ __forceinline__ u16 f2b(float f) {   // rne f32->bf16
    unsigned u = __builtin_bit_cast(unsigned, f);
    unsigned r = (u + 0x7FFFu + ((u >> 16) & 1u)) >> 16;
    return (u16)r;
}
__device__ __forceinline__ float fsigm(float x) {
    return __builtin_amdgcn_rcpf(1.f + __expf(-x));
}
__device__ __forceinline__ float ftanh2(float x) {
    return 2.f * __builtin_amdgcn_rcpf(1.f + __expf(-2.f * x)) - 1.f;
}
__device__ __forceinline__ bf16x8 ld_frag(const u16* p) {
    u32x4 v = *(const u32x4*)p;
    return __builtin_bit_cast(bf16x8, v);
}
__device__ __forceinline__ f32x4 mfma16(bf16x8 a, bf16x8 b, f32x4 c) {
    return __builtin_amdgcn_mfma_f32_16x16x32_bf16(a, b, c, 0, 0, 0);
}
// load 8 f32, convert to 8 bf16 packed in u32x4
__device__ __forceinline__ u32x4 cvt8(const float* p) {
    f32x4 a = *(const f32x4*)p;
    f32x4 b = *(const f32x4*)(p + 4);
    u32x4 r;
    r.x = (unsigned)f2b(a[0]) | ((unsigned)f2b(a[1]) << 16);
    r.y = (unsigned)f2b(a[2]) | ((unsigned)f2b(a[3]) << 16);
    r.z = (unsigned)f2b(b[0]) | ((unsigned)f2b(b[1]) << 16);
    r.w = (unsigned)f2b(b[2]) | ((unsigned)f2b(b[3]) << 16);
    return r;
}

// ALL cross-block communication at system scope (sc0 sc1): L1+L2 bypass, the
// memory-side Infinity Cache is the coherence point. Proven replay-safe (r2/r3/r6).
// Lessons locked in: L2-scope (sc0-only) is NOT replay-safe (r5); bulk tagged-data
// polling regresses (r7); per-wave flags + hot poll regress (r8). Protocol below
// is r6's verbatim; only the h-exchange LAYOUT changed (chunked, full-line stores).
__device__ __forceinline__ u32x4 ld16_coh(const u16* p) {
    u32x4 v;
    asm volatile("global_load_dwordx4 %0, %1, off sc0 sc1" : "=v"(v) : "v"(p));
    return v;
}
__device__ __forceinline__ void st2_coh(u16* p, u16 val) {
    unsigned v = val;
    asm volatile("global_store_short %0, %1, off sc0 sc1" :: "v"(p), "v"(v) : "memory");
}
__device__ __forceinline__ void st4_coh(unsigned* p, unsigned v) {
    asm volatile("global_store_dword %0, %1, off sc0 sc1" :: "v"(p), "v"(v) : "memory");
}
__device__ __forceinline__ unsigned ld4_coh_wait(const unsigned* p) {
    unsigned v;
    asm volatile("global_load_dword %0, %1, off sc0 sc1\n\ts_waitcnt vmcnt(0)"
                 : "=v"(v) : "v"(p) : "memory");
    return v;
}

// ---------- transpose+cast: out_bf16[c][r] = f2b(in_f32[r][c]) ----------
__global__ void k_transpose(const float* __restrict__ in, u16* __restrict__ out, int R, int C) {
    __shared__ u16 tl[64][65];
    int tx = threadIdx.x, ty = threadIdx.y;
    int c0 = blockIdx.x * 64, r0 = blockIdx.y * 64;
#pragma unroll
    for (int i = 0; i < 16; i++) {
        int a = ty + i * 4;
        tl[a][tx] = f2b(in[(size_t)(r0 + a) * C + c0 + tx]);
    }
    __syncthreads();
#pragma unroll
    for (int i = 0; i < 16; i++) {
        int a = ty + i * 4;
        out[(size_t)(c0 + a) * R + r0 + tx] = tl[tx][a];
    }
}

// ---------- field GEMM: ft = sigmoid(F@W1[:, :1024]+b) * tanh(F@W1[:, 1024:]+b) ----------
// Rows (bb, t) with t >= len[bb] are dead downstream — skip tiles entirely past len.
__global__ __launch_bounds__(256) void k_field(const float* __restrict__ F, const u16* __restrict__ W1t,
                                               const float* __restrict__ bW1, const int* __restrict__ len,
                                               u16* __restrict__ ftw) {
    int m0 = blockIdx.y * 128;
    if ((m0 & 511) >= len[m0 >> 9]) return;   // whole tile beyond this row's length
    int n0 = blockIdx.x * 64;
    __shared__ u16 As[128 * 40];
    __shared__ u16 Bs[128 * 40];
    int tid = threadIdx.x, w = tid >> 6, lane = tid & 63, quad = lane >> 4, l16 = lane & 15;
    f32x4 acc[2][8];
#pragma unroll
    for (int mt = 0; mt < 2; mt++)
#pragma unroll
        for (int nt = 0; nt < 8; nt++) acc[mt][nt] = (f32x4){0.f, 0.f, 0.f, 0.f};

    for (int kc = 0; kc < 8; kc++) {
        __syncthreads();
#pragma unroll
        for (int it = 0; it < 2; it++) {
            int q = tid + it * 256, row = q >> 2, sub = q & 3;
            u32x4 va = cvt8(F + (size_t)(m0 + row) * 256 + kc * 32 + sub * 8);
            *(u32x4*)(As + row * 40 + sub * 8) = va;
            int brow = (row < 64) ? (n0 + row) : (1024 + n0 + row - 64);
            u32x4 vb = *(const u32x4*)(W1t + (size_t)brow * 256 + kc * 32 + sub * 8);
            *(u32x4*)(Bs + row * 40 + sub * 8) = vb;
        }
        __syncthreads();
        bf16x8 af[2], bfr[8];
#pragma unroll
        for (int mt = 0; mt < 2; mt++) af[mt] = ld_frag(As + (w * 32 + mt * 16 + l16) * 40 + quad * 8);
#pragma unroll
        for (int nt = 0; nt < 8; nt++) bfr[nt] = ld_frag(Bs + (nt * 16 + l16) * 40 + quad * 8);
#pragma unroll
        for (int mt = 0; mt < 2; mt++)
#pragma unroll
            for (int nt = 0; nt < 8; nt++) acc[mt][nt] = mfma16(af[mt], bfr[nt], acc[mt][nt]);
    }
#pragma unroll
    for (int nth = 0; nth < 4; nth++) {
        float br = bW1[n0 + nth * 16 + l16];
        float bd = bW1[1024 + n0 + nth * 16 + l16];
#pragma unroll
        for (int mt = 0; mt < 2; mt++) {
#pragma unroll
            for (int j = 0; j < 4; j++) {
                int r = m0 + w * 32 + mt * 16 + quad * 4 + j;
                float rv = acc[mt][nth][j] + br;
                float dv = acc[mt][nth + 4][j] + bd;
                ftw[(size_t)r * 1024 + n0 + nth * 16 + l16] = f2b(fsigm(rv) * ftanh2(dv));
            }
        }
    }
}

// ---------- x GEMM: gx[r][H][g] = X@W[:1024,:] + bW (gate-interleaved, bf16 store) ----------
__global__ __launch_bounds__(256) void k_xgemm(const float* __restrict__ X, const u16* __restrict__ Wt,
                                               const float* __restrict__ bWv, const int* __restrict__ len,
                                               u16* __restrict__ gx) {
    int m0 = blockIdx.y * 128;
    if ((m0 & 511) >= len[m0 >> 9]) return;   // whole tile beyond this row's length
    int n0 = blockIdx.x * 128;
    __shared__ u16 As[128 * 40];
    __shared__ u16 Bs[128 * 40];
    int tid = threadIdx.x, w = tid >> 6, lane = tid & 63, quad = lane >> 4, l16 = lane & 15;
    int mq = (w & 1) * 64, nq = (w >> 1) * 64;
    f32x4 acc[4][4];
#pragma unroll
    for (int mt = 0; mt < 4; mt++)
#pragma unroll
        for (int nt = 0; nt < 4; nt++) acc[mt][nt] = (f32x4){0.f, 0.f, 0.f, 0.f};

    for (int kc = 0; kc < 32; kc++) {
        __syncthreads();
#pragma unroll
        for (int it = 0; it < 2; it++) {
            int q = tid + it * 256, row = q >> 2, sub = q & 3;
            u32x4 va = cvt8(X + (size_t)(m0 + row) * 1024 + kc * 32 + sub * 8);
            *(u32x4*)(As + row * 40 + sub * 8) = va;
            u32x4 vb = *(const u32x4*)(Wt + (size_t)(n0 + row) * 2048 + kc * 32 + sub * 8);
            *(u32x4*)(Bs + row * 40 + sub * 8) = vb;
        }
        __syncthreads();
        bf16x8 af[4], bfr[4];
#pragma unroll
        for (int mt = 0; mt < 4; mt++) af[mt] = ld_frag(As + (mq + mt * 16 + l16) * 40 + quad * 8);
#pragma unroll
        for (int nt = 0; nt < 4; nt++) bfr[nt] = ld_frag(Bs + (nq + nt * 16 + l16) * 40 + quad * 8);
#pragma unroll
        for (int mt = 0; mt < 4; mt++)
#pragma unroll
            for (int nt = 0; nt < 4; nt++) acc[mt][nt] = mfma16(af[mt], bfr[nt], acc[mt][nt]);
    }
#pragma unroll
    for (int nt = 0; nt < 4; nt++) {
        int gcol = n0 + nq + nt * 16 + l16;
        int hcol = gcol & 1023, g = gcol >> 10;
        float bw = bWv[gcol];
#pragma unroll
        for (int mt = 0; mt < 4; mt++) {
#pragma unroll
            for (int j = 0; j < 4; j++) {
                int r = m0 + mq + mt * 16 + quad * 4 + j;
                gx[(size_t)r * 4096 + hcol * 4 + g] = f2b(acc[mt][nt][j] + bw);
            }
        }
    }
}

// ---------- zero-init recurrent state (+ flag region overlaying cbuf in coop path) ----------
__global__ void k_zero(u16* __restrict__ hbuf, float* __restrict__ cbuf, float* __restrict__ hfin) {
    int idx = blockIdx.x * 1024 + threadIdx.x;  // 64k threads
    hbuf[idx] = 0; hbuf[65536 + idx] = 0;
    cbuf[idx] = 0.f; hfin[idx] = 0.f;
}

// ---------- persistent cooperative LSTM: all 512 steps in one kernel ----------
// grid = 256 blocks = 4 bbg (16-row batch slices) x 64 wg (16 H-cols).
// Protocol = r6 verbatim (drain -> __syncthreads -> tid0 flag -> per-wave poll of
// 16 producers, all sc0|sc1). ONE change vs r6: h exchange uses a producer-major
// CHUNKED layout hc[2][bbg][wg][16 row][16 col] — each block stores its 256
// h-values at chunk+tid (one contiguous 512B = 4 FULL cache lines, coalesced)
// instead of 16 scattered 32B partial-line fragments. Consumer fragment loads
// stay single 16B reads: for K-slice kk, lane reads
//   chunk[prod = w*16 + 2kk + (quad>>1)][l16][(quad&1)*8]
// which is bit-identical to the old av[kk] content.
__global__ __launch_bounds__(256, 1) void k_lstm(const u16* __restrict__ Wt, const u16* __restrict__ gx,
                                                 const u16* __restrict__ ftw, const int* __restrict__ len,
                                                 float* __restrict__ out, u16* __restrict__ hbuf,
                                                 unsigned* __restrict__ bar) {
    __shared__ __align__(16) float red[4 * 64 * 20];
    int tid = threadIdx.x;
    int w = tid >> 6, lane = tid & 63, quad = lane >> 4, l16 = lane & 15;
    int blk = blockIdx.x;
    int bbg = blk & 3, wg = blk >> 2;

    // ---- one-time: weights into registers. wave w owns K range [w*256, w*256+256) ----
    bf16x8 breg[8][4];
#pragma unroll
    for (int kk = 0; kk < 8; kk++)
#pragma unroll
        for (int nt = 0; nt < 4; nt++) {
            size_t gcol = (size_t)nt * 1024 + wg * 16 + l16;   // gate nt, hcol wg*16+l16
            breg[kk][nt] = ld_frag(Wt + gcol * 2048 + 1024 + w * 256 + kk * 32 + quad * 8);
        }

    // per-thread epilogue ownership: one (bb, Hcol) pair
    int bbl = tid >> 4, hc = tid & 15;
    int bb = bbg * 16 + bbl;
    int Hcol = wg * 16 + hc;
    int mylen = len[bb];
    float hreg = 0.f, creg = 0.f;

    // chunked h addressing (u16 units): parity stride 65536, group stride 16384
    // consumer: base offset within group for this lane (prod advances by 2 per kk)
    int cbase = (w * 16 + (quad >> 1)) * 256 + l16 * 16 + (quad & 1) * 8;
    // producer: my chunk slot + tid
    int pbase = (bbg * 64 + wg) * 256 + tid;

    // flag lines: (bbg*64 + wg) * 128B, inside zeroed cbuf region
    unsigned* myflag = bar + (((size_t)bbg << 6) | (size_t)wg) * 32;
    // per-wave producer poll: wave w waits on slots [16w, 16w+16) of its group
    const unsigned* pollw = bar + (((size_t)bbg << 6) | (size_t)(w * 16 + (lane & 15))) * 32;

    // prefetch t=0 epilogue operands
    u32x2 gq = *(const u32x2*)(gx + ((size_t)bb * 512) * 4096 + (size_t)Hcol * 4);
    float ftv = b2f(ftw[((size_t)bb * 512) * 1024 + Hcol]);

    for (int t = 0; t < 512; t++) {
        const u16* hbg = hbuf + (t & 1) * 65536 + bbg * 16384;       // this group's chunks
        u16* hst = hbuf + ((t + 1) & 1) * 65536 + pbase;             // my chunk slot

        // ---- h @ Wh partial. A fragments read coherently from L3 (chunked layout).
        u32x4 av[8];
#pragma unroll
        for (int kk = 0; kk < 8; kk++)
            av[kk] = ld16_coh(hbg + cbase + kk * 512);
        asm volatile("s_waitcnt vmcnt(0)" ::: "memory");
        __builtin_amdgcn_sched_barrier(0);   // keep MFMAs below the waitcnt (rule #18)

        f32x4 acc[4];
#pragma unroll
        for (int nt = 0; nt < 4; nt++) acc[nt] = (f32x4){0.f, 0.f, 0.f, 0.f};
#pragma unroll
        for (int kk = 0; kk < 8; kk++) {
            bf16x8 af = __builtin_bit_cast(bf16x8, av[kk]);
#pragma unroll
            for (int nt = 0; nt < 4; nt++) acc[nt] = mfma16(af, breg[kk][nt], acc[nt]);
        }
#pragma unroll
        for (int nt = 0; nt < 4; nt++)
            *(f32x4*)&red[(w * 64 + nt * 16 + l16) * 20 + quad * 4] = acc[nt];
        __syncthreads();

        // cross-wave K-reduction (same order as fallback k_step: w = 0..3)
        float G[4];
#pragma unroll
        for (int g = 0; g < 4; g++) {
            int c = g * 16 + hc;
            G[g] = red[(0 * 64 + c) * 20 + bbl] + red[(1 * 64 + c) * 20 + bbl]
                 + red[(2 * 64 + c) * 20 + bbl] + red[(3 * 64 + c) * 20 + bbl];
        }
        float iv = G[0] + b2f((u16)(gq.x & 0xffff));
        float jv = G[1] + b2f((u16)(gq.x >> 16));
        float fv = G[2] + b2f((u16)(gq.y & 0xffff));
        float ov = G[3] + b2f((u16)(gq.y >> 16));
        float cn = fsigm(fv + 1.f) * creg + fsigm(iv) * ftanh2(jv) + ftv;
        float hn = fsigm(ov) * ftanh2(cn);
        bool act = t < mylen;
        // plain cached store: fast L2 ack so the drain below mostly waits on h
        out[(size_t)bb * 524288 + (size_t)t * 1024 + Hcol] = act ? hn : 0.f;
        hreg = act ? hn : hreg;
        creg = act ? cn : creg;
        // h broadcast: contiguous chunk store (4 full lines per block), write-through
        st2_coh(hst, f2b(hreg));

        if (t != 511) {
            // drain h to the coherence point, converge block, publish flag
            asm volatile("s_waitcnt vmcnt(0)" ::: "memory");
            __syncthreads();
            unsigned gen = (unsigned)(t + 1);
            if (tid == 0) st4_coh(myflag, gen);
            // prefetch next-step operands; latency hides under the poll
            size_t rowi = (size_t)bb * 512 + (t + 1);
            gq = *(const u32x2*)(gx + rowi * 4096 + (size_t)Hcol * 4);
            ftv = b2f(ftw[rowi * 1024 + Hcol]);
            // per-wave poll of this wave's 16 producers; no trailing barrier
            for (;;) {
                unsigned v = ld4_coh_wait(pollw);
                if (__all((int)(v >= gen))) break;
                __builtin_amdgcn_s_sleep(1);
            }
        }
    }
    // final states straight from registers (replaces k_fin)
    out[33554432 + (size_t)bb * 1024 + Hcol] = hreg;
    out[33554432 + 65536 + (size_t)bb * 1024 + Hcol] = creg;
}

// ---------- fallback: one LSTM time-step (512 sequential launches) ----------
__global__ __launch_bounds__(256) void k_step(const u16* __restrict__ Wt, const u16* __restrict__ gx,
                                              const u16* __restrict__ ftw, const int* __restrict__ len,
                                              float* __restrict__ out, u16* __restrict__ hbuf,
                                              float* __restrict__ cbuf, float* __restrict__ hfin, int t) {
    int wg = blockIdx.x;
    int tid = threadIdx.x, w = tid >> 6, lane = tid & 63, quad = lane >> 4, l16 = lane & 15;
    __shared__ float red[4 * 64 * 68];  // [wave][c][row(+pad)]

    const u16* hb = hbuf + (t & 1) * 65536;
    u16* hbn = hbuf + ((t + 1) & 1) * 65536;

    f32x4 acc[4][4];
#pragma unroll
    for (int mt = 0; mt < 4; mt++)
#pragma unroll
        for (int nt = 0; nt < 4; nt++) acc[mt][nt] = (f32x4){0.f, 0.f, 0.f, 0.f};

#pragma unroll
    for (int kk = 0; kk < 8; kk++) {
        bf16x8 af[4], bq[4];
#pragma unroll
        for (int mt = 0; mt < 4; mt++)
            af[mt] = ld_frag(hb + (mt * 16 + l16) * 1024 + w * 256 + kk * 32 + quad * 8);
#pragma unroll
        for (int nt = 0; nt < 4; nt++) {
            int c = nt * 16 + l16;
            int gcol = (c & 3) * 1024 + wg * 16 + (c >> 2);
            bq[nt] = ld_frag(Wt + (size_t)gcol * 2048 + 1024 + w * 256 + kk * 32 + quad * 8);
        }
#pragma unroll
        for (int mt = 0; mt < 4; mt++)
#pragma unroll
            for (int nt = 0; nt < 4; nt++) acc[mt][nt] = mfma16(af[mt], bq[nt], acc[mt][nt]);
    }

#pragma unroll
    for (int mt = 0; mt < 4; mt++)
#pragma unroll
        for (int nt = 0; nt < 4; nt++)
            *(f32x4*)&red[(w * 64 + nt * 16 + l16) * 68 + mt * 16 + quad * 4] = acc[mt][nt];
    __syncthreads();

    int hc = tid & 15, rg = tid >> 4;
    int Hcol = wg * 16 + hc;
    f32x4 Gv[4];
#pragma unroll
    for (int g = 0; g < 4; g++) {
        int c = hc * 4 + g;
        f32x4 s = *(f32x4*)&red[(0 * 64 + c) * 68 + rg * 4];
#pragma unroll
        for (int wq = 1; wq < 4; wq++) s += *(f32x4*)&red[(wq * 64 + c) * 68 + rg * 4];
        Gv[g] = s;
    }

#pragma unroll
    for (int j = 0; j < 4; j++) {
        int bb = rg * 4 + j;
        size_t rowi = (size_t)bb * 512 + t;
        u32x2 gq = *(const u32x2*)(gx + rowi * 4096 + (size_t)Hcol * 4);
        float iv = Gv[0][j] + b2f((u16)(gq.x & 0xffff));
        float jv = Gv[1][j] + b2f((u16)(gq.x >> 16));
        float fv = Gv[2][j] + b2f((u16)(gq.y & 0xffff));
        float ov = Gv[3][j] + b2f((u16)(gq.y >> 16));
        float ftv = b2f(ftw[rowi * 1024 + Hcol]);
        float cprev = cbuf[bb * 1024 + Hcol];
        float hprev = hfin[bb * 1024 + Hcol];
        float cn = fsigm(fv + 1.f) * cprev + fsigm(iv) * ftanh2(jv) + ftv;
        float hn = fsigm(ov) * ftanh2(cn);
        bool act = t < len[bb];
        out[(size_t)bb * 524288 + (size_t)t * 1024 + Hcol] = act ? hn : 0.f;
        hbn[bb * 1024 + Hcol] = f2b(act ? hn : hprev);
        cbuf[bb * 1024 + Hcol] = act ? cn : cprev;
        hfin[bb * 1024 + Hcol] = act ? hn : hprev;
    }
}

// ---------- fallback final state writeout (f32) ----------
__global__ void k_fin(const float* __restrict__ hfin, const float* __restrict__ cbuf,
                      float* __restrict__ out) {
    int idx = blockIdx.x * 1024 + threadIdx.x;  // 65536
    out[33554432 + idx] = hfin[idx];
    out[33554432 + 65536 + idx] = cbuf[idx];
}

extern "C" void kernel_launch(void* const* d_in, const int* in_sizes, int n_in,
                              void* d_out, int out_size, void* d_ws, size_t ws_size,
                              hipStream_t stream) {
    (void)in_sizes; (void)n_in; (void)out_size;
    if (ws_size < WS_NEED) return;

    const float* X   = (const float*)d_in[0];
    const float* F   = (const float*)d_in[1];
    const int*   len = (const int*)d_in[2];
    const float* W   = (const float*)d_in[3];
    const float* bW  = (const float*)d_in[4];
    const float* W1  = (const float*)d_in[5];
    const float* bW1 = (const float*)d_in[6];
    float* out = (float*)d_out;

    char* ws = (char*)d_ws;
    u16*   gx   = (u16*)(ws + GX_OFF);
    u16*   ftw  = (u16*)(ws + FT_OFF);
    u16*   Wt   = (u16*)(ws + WT_OFF);
    u16*   W1t  = (u16*)(ws + W1T_OFF);
    float* cbuf = (float*)(ws + CB_OFF);   // overlays W1t (dead after k_field); flag region in coop path
    float* hfin = (float*)(ws + HF_OFF);   // overlays W1t (dead after k_field)
    u16*   hbuf = (u16*)(ws + HB_OFF);

    k_transpose<<<dim3(64, 32), dim3(64, 4), 0, stream>>>(W, Wt, 2048, 4096);
    k_transpose<<<dim3(32, 4), dim3(64, 4), 0, stream>>>(W1, W1t, 256, 2048);
    k_field<<<dim3(16, 256), 256, 0, stream>>>(F, W1t, bW1, len, ftw);
    k_xgemm<<<dim3(32, 256), 256, 0, stream>>>(X, Wt, bW, len, gx);
    k_zero<<<64, 1024, 0, stream>>>(hbuf, cbuf, hfin);   // zeroes hbuf (both layouts) + flag region

    unsigned* bar = (unsigned*)cbuf;
    void* args[7] = {(void*)&Wt, (void*)&gx, (void*)&ftw, (void*)&len,
                     (void*)&out, (void*)&hbuf, (void*)&bar};
    hipError_t e = hipLaunchCooperativeKernel((const void*)k_lstm, dim3(NBLK), dim3(256),
                                              args, 0, stream);
    if (e != hipSuccess) {
        // fallback: proven 512-launch path (cbuf/hfin still zeroed and unaliased here)
        for (int t = 0; t < 512; t++)
            k_step<<<64, 256, 0, stream>>>(Wt, gx, ftw, len, out, hbuf, cbuf, hfin, t);
        k_fin<<<64, 1024, 0, stream>>>(hfin, cbuf, out);
    }
}